// Round 8
// baseline (1089.804 us; speedup 1.0000x reference)
//
#include <hip/hip_runtime.h>
#include <stdint.h>

// Problem constants (match reference)
#define BB     4
#define CC     32
#define HH     32
#define WW     1024
#define PATCH  21
#define RAD    10
#define PADW   20                 // DIL*RAD : max displacement
#define CSTR   (HH * WW)          // channel stride (also the out pj stride)

// R7 POST-MORTEM: XCD-pinned decode worked (FETCH 500->18 MB, all L2) but the
// kernel stayed 175 us: ~3800 cyc/pass vs ~500 cyc of work -> barrier-
// serialization bound (16 x {syncthreads + vmcnt(0) drain} with 3.5 blocks/CU).
// R8: LDS/staging DELETED. x2 windows are read directly from global (L1/L2-
// served; u0 = 8tw+2pjb-20 is 4-aligned since pjb is even, and 0/1024 are
// granule-aligned, so each float4 is fully in- or out-of-range -> 3 predicated
// loads replace staging + swizzle + zero-prologue). Zero barriers; latency is
// hidden by occupancy (no LDS -> 5 blocks/CU at (256,5)). acc=32 envelope kept.
__global__ __launch_bounds__(256, 5)
void corr_kernel(const float* __restrict__ x1, const float* __restrict__ x2,
                 float* __restrict__ out) {
    const int tid = threadIdx.x;
    const int tw  = tid & 127;             // w-position (w = 8*tw)
    const int th2 = tid >> 7;              // wave-uniform tap-pair select

    // ---- dispatch decode (R7-proven): lid -> (r2, b, s, z), XCD-pinned ----
    const int lid    = blockIdx.x;         // 0..13823
    const int xcd    = lid & 7;            // XCD slot (m09 round-robin)
    const int t8     = lid >> 3;
    const int sharer = t8 % 48;            // 48 sharers of one (b,r2) row
    const int rowd   = t8 / 48;
    const int row    = rowd * 8 + xcd;     // row = 4*r2i + b
    const int r2i    = row >> 2;
    const int b      = row & 3;
    const int s      = sharer & 7;         // chain pair-slot
    const int z      = sharer >> 3;        // tap group 0..5
    const int r2     = r2i - PADW;         // -20..51

    const int pi_hi = min(20, (r2 + 20) >> 1);
    const int pi_lo = max(0, (r2 - 10) >> 1);
    const int L     = pi_hi - pi_lo + 1;        // chain length
    const int e0    = 2 * s;
    if (e0 >= L) return;                        // empty slot

    const int  pi0  = pi_hi - e0;
    const int  h0   = r2 + 20 - 2 * pi0;        // in [0,31]
    const bool has1 = (e0 + 1) < L;
    const int  pi1  = pi0 - 1;
    const int  h1   = h0 + 2;

    const int pjb = 4 * z + 2 * th2;            // even tap base
    if (pjb > 20) return;                       // z=5,th2=1: no taps (no barriers exist)
    const bool st1 = (pjb + 1 <= 20);           // tap 21 doesn't exist (pjb=20)
    const int  w8  = tw * 8;

    float* out0 = out + (((size_t)(b * PATCH * PATCH + pi0 * PATCH + pjb)) * HH + h0) * WW + w8;
    float* out1 = out + (((size_t)(b * PATCH * PATCH + pi1 * PATCH + pjb)) * HH + h1) * WW + w8;

    if ((unsigned)r2 >= (unsigned)HH) {
        // x2 row OOB: outputs are zero for all taps.
        float4 zv = make_float4(0.f, 0.f, 0.f, 0.f);
#pragma unroll
        for (int j = 0; j < 2; j++) {
            if (j == 0 || st1) {
                *(float4*)(out0 + (size_t)j * CSTR)     = zv;
                *(float4*)(out0 + (size_t)j * CSTR + 4) = zv;
                if (has1) {
                    *(float4*)(out1 + (size_t)j * CSTR)     = zv;
                    *(float4*)(out1 + (size_t)j * CSTR + 4) = zv;
                }
            }
        }
        return;
    }

    // Window granules: floats u0..u0+11 cover taps {pjb, pjb+1} x k=0..7
    // (f = k + 2j <= 9). u0 is 4-aligned; each granule fully in/out of [0,1024).
    const int  u0 = w8 + 2 * pjb - PADW;
    const bool v0 = (u0     >= 0) && (u0     <= WW - 4);
    const bool v1 = (u0 + 4 >= 0) && (u0 + 4 <= WW - 4);
    const bool v2 = (u0 + 8 >= 0) && (u0 + 8 <= WW - 4);

    const float* x2p = x2 + ((size_t)(b * CC) * HH + r2) * WW + u0;   // + c*CSTR
    const float* xap = x1 + ((size_t)(b * CC) * HH + h0) * WW + w8;   // + c*CSTR
    const float* xbp = has1 ? (xap + 2 * WW) : xap;  // clamp: stores skipped if !has1

    float acc0[2][8], acc1[2][8];
#pragma unroll
    for (int j = 0; j < 2; j++)
#pragma unroll
        for (int k = 0; k < 8; k++) { acc0[j][k] = 0.f; acc1[j][k] = 0.f; }

    const float4 zv4 = make_float4(0.f, 0.f, 0.f, 0.f);
    for (int c = 0; c < CC; ++c) {
        float4 wv0 = v0 ? *(const float4*)(x2p)     : zv4;
        float4 wv1 = v1 ? *(const float4*)(x2p + 4) : zv4;
        float4 wv2 = v2 ? *(const float4*)(x2p + 8) : zv4;
        float win[12] = {wv0.x, wv0.y, wv0.z, wv0.w,
                         wv1.x, wv1.y, wv1.z, wv1.w,
                         wv2.x, wv2.y, wv2.z, wv2.w};

        float4 a00 = *(const float4*)xap, a01 = *(const float4*)(xap + 4);
        float4 a10 = *(const float4*)xbp, a11 = *(const float4*)(xbp + 4);
        const float a0[8] = {a00.x, a00.y, a00.z, a00.w, a01.x, a01.y, a01.z, a01.w};
        const float a1[8] = {a10.x, a10.y, a10.z, a10.w, a11.x, a11.y, a11.z, a11.w};

        // tap pjb+j, output w8+k -> window float k + 2j (static index, max 9)
#pragma unroll
        for (int j = 0; j < 2; j++)
#pragma unroll
            for (int k = 0; k < 8; k++) {
                const float wv = win[k + 2 * j];
                acc0[j][k] = fmaf(a0[k], wv, acc0[j][k]);
                acc1[j][k] = fmaf(a1[k], wv, acc1[j][k]);
            }

        x2p += CSTR; xap += CSTR; xbp += CSTR;
    }

    const float inv_c = 1.0f / (float)CC;
#pragma unroll
    for (int j = 0; j < 2; j++) {
        if (j == 0 || st1) {
            float4 o0, o1, q0, q1;
            float* po0 = (float*)&o0; float* po1 = (float*)&o1;
            float* pq0 = (float*)&q0; float* pq1 = (float*)&q1;
#pragma unroll
            for (int k = 0; k < 4; k++) {
                float v0o = acc0[j][k]     * inv_c;
                float v1o = acc0[j][4 + k] * inv_c;
                float u0o = acc1[j][k]     * inv_c;
                float u1o = acc1[j][4 + k] * inv_c;
                po0[k] = v0o > 0.f ? v0o : 0.1f * v0o;
                po1[k] = v1o > 0.f ? v1o : 0.1f * v1o;
                pq0[k] = u0o > 0.f ? u0o : 0.1f * u0o;
                pq1[k] = u1o > 0.f ? u1o : 0.1f * u1o;
            }
            *(float4*)(out0 + (size_t)j * CSTR)     = o0;
            *(float4*)(out0 + (size_t)j * CSTR + 4) = o1;
            if (has1) {
                *(float4*)(out1 + (size_t)j * CSTR)     = q0;
                *(float4*)(out1 + (size_t)j * CSTR + 4) = q1;
            }
        }
    }
}

extern "C" void kernel_launch(void* const* d_in, const int* in_sizes, int n_in,
                              void* d_out, int out_size, void* d_ws, size_t ws_size,
                              hipStream_t stream) {
    const float* x1 = (const float*)d_in[0];
    const float* x2 = (const float*)d_in[1];
    float* out = (float*)d_out;

    // 1-D grid, XCD-pinned decode inside the kernel: 72 r2 x 4 b x 8 slots x 6 z.
    dim3 grid(72 * 4 * 8 * 6, 1, 1);   // 13824 blocks
    dim3 block(256, 1, 1);
    corr_kernel<<<grid, block, 0, stream>>>(x1, x2, out);
}